// Round 1
// baseline (788.993 us; speedup 1.0000x reference)
//
#include <hip/hip_runtime.h>
#include <math.h>

#define B_ 4
#define L_ 4800
#define S_ 4800
#define C_ 256
#define THR 0.2f
#define SIM_SCALE 0.0390625f   // 1/(256*0.1)
#define KPT_SCALE 8.0f
#define CAND_CAP 262144u

typedef short bf16x8 __attribute__((ext_vector_type(8)));   // 8 bf16 in 4 VGPRs
typedef float f32x4  __attribute__((ext_vector_type(4)));

// ---------------- ws layout (float slots) ----------------
// [0,19200)        rowsum   (B*L)
// [19200,38400)    colsum   (B*S)
// [38400,57600)    rowmax   (B*L)   (f32 bits via uint atomicMax, values >= 0)
// [57600,76800)    colmax   (B*S)
// [76800,115200)   bestkey  (B*L u64: score_bits<<32 | ~s)
// [115200]         cand_cnt (uint)
// [115208, +CAND_CAP)  cand list (uint packed b<<26|l<<13|s)
// then f0b bf16 (B*L*C), f1b bf16 (B*S*C)
#define WS_ZERO_N 115204
#define WS_CAND_CNT 115200
#define WS_CAND_LIST 115208
#define WS_BF16 (115208 + CAND_CAP)

__device__ __forceinline__ unsigned short f2bf(float x) {
    union { float f; unsigned int u; } v; v.f = x;
    unsigned int r = v.u + 0x7fffu + ((v.u >> 16) & 1u);   // RNE
    return (unsigned short)(r >> 16);
}

__global__ void k_init(float* ws) {
    int i = blockIdx.x * blockDim.x + threadIdx.x;
    if (i < WS_ZERO_N) ws[i] = 0.0f;
}

__global__ void k_cast(const float* __restrict__ f0, const float* __restrict__ f1,
                       ushort* __restrict__ f0b, ushort* __restrict__ f1b) {
    int i = blockIdx.x * blockDim.x + threadIdx.x;   // float4 index
    if (i * 4 >= B_ * L_ * C_) return;
    float4 a = ((const float4*)f0)[i];
    float4 b = ((const float4*)f1)[i];
    ushort4 oa, ob;
    oa.x = f2bf(a.x); oa.y = f2bf(a.y); oa.z = f2bf(a.z); oa.w = f2bf(a.w);
    ob.x = f2bf(b.x); ob.y = f2bf(b.y); ob.z = f2bf(b.z); ob.w = f2bf(b.w);
    ((ushort4*)f0b)[i] = oa;
    ((ushort4*)f1b)[i] = ob;
}

// Shared MFMA core: each wave computes a 64x64 tile of p = exp(sim); block = 4
// waves covering 64(l) x 256(s).
// PASS 0: accumulate rowsum/colsum of p (no store).
// PASS 1: conf = p^2/(rowsum*colsum); store conf; rowmax/colmax atomicMax;
//         sparse candidate extraction (conf>THR & borders).
template <int PASS>
__global__ __launch_bounds__(256) void k_gemm(
        const ushort* __restrict__ f0b, const ushort* __restrict__ f1b,
        float* __restrict__ conf,
        float* __restrict__ rowsum, float* __restrict__ colsum,
        float* __restrict__ rowmax, float* __restrict__ colmax,
        unsigned* __restrict__ cand_cnt, unsigned* __restrict__ cand_list) {
    const int b    = blockIdx.z;
    const int l0   = blockIdx.y * 64;
    const int wave = threadIdx.x >> 6;
    const int s0   = blockIdx.x * 256 + wave * 64;
    if (s0 >= S_) return;                       // no __syncthreads in kernel: safe
    const int lane = threadIdx.x & 63;
    const int quad = lane >> 4;
    const int lr   = lane & 15;

    const ushort* A  = f0b + (size_t)b * L_ * C_;
    const ushort* Bm = f1b + (size_t)b * S_ * C_;

    f32x4 acc[4][4];
#pragma unroll
    for (int r = 0; r < 4; r++)
#pragma unroll
        for (int c = 0; c < 4; c++) acc[r][c] = (f32x4){0.f, 0.f, 0.f, 0.f};

    for (int kk = 0; kk < C_; kk += 32) {
        bf16x8 af[4], bf[4];
#pragma unroll
        for (int r = 0; r < 4; r++) {
            const int row = l0 + r * 16 + lr;                // A[m=lane&15][k=quad*8+j]
            af[r] = *(const bf16x8*)(A + (size_t)row * C_ + kk + quad * 8);
        }
#pragma unroll
        for (int c = 0; c < 4; c++) {
            const int srow = s0 + c * 16 + lr;               // B[k=quad*8+j][n=lane&15]
            bf[c] = *(const bf16x8*)(Bm + (size_t)srow * C_ + kk + quad * 8);
        }
#pragma unroll
        for (int r = 0; r < 4; r++)
#pragma unroll
            for (int c = 0; c < 4; c++)
                acc[r][c] = __builtin_amdgcn_mfma_f32_16x16x32_bf16(af[r], bf[c], acc[r][c], 0, 0, 0);
    }

    // p = exp(sim)
#pragma unroll
    for (int r = 0; r < 4; r++)
#pragma unroll
        for (int c = 0; c < 4; c++)
#pragma unroll
            for (int g = 0; g < 4; g++)
                acc[r][c][g] = __expf(acc[r][c][g] * SIM_SCALE);

    if constexpr (PASS == 0) {
        // row sums (over this wave's 64 s-cols): reduce over c and the 16 lanes lr
#pragma unroll
        for (int r = 0; r < 4; r++)
#pragma unroll
            for (int g = 0; g < 4; g++) {
                float v = acc[r][0][g] + acc[r][1][g] + acc[r][2][g] + acc[r][3][g];
                v += __shfl_xor(v, 1, 64);
                v += __shfl_xor(v, 2, 64);
                v += __shfl_xor(v, 4, 64);
                v += __shfl_xor(v, 8, 64);
                if (lr == 0) {
                    const int row = l0 + r * 16 + quad * 4 + g;
                    atomicAdd(rowsum + b * L_ + row, v);
                }
            }
        // col sums (over this wave's 64 l-rows): reduce over r,g and the 4 quads
#pragma unroll
        for (int c = 0; c < 4; c++) {
            float v = 0.f;
#pragma unroll
            for (int r = 0; r < 4; r++)
#pragma unroll
                for (int g = 0; g < 4; g++) v += acc[r][c][g];
            v += __shfl_xor(v, 16, 64);
            v += __shfl_xor(v, 32, 64);
            if (quad == 0) atomicAdd(colsum + b * S_ + s0 + c * 16 + lr, v);
        }
    } else {
        // conf = p^2 / (rowsum * colsum)
        float irs[4][4];
#pragma unroll
        for (int r = 0; r < 4; r++)
#pragma unroll
            for (int g = 0; g < 4; g++)
                irs[r][g] = 1.0f / rowsum[b * L_ + l0 + r * 16 + quad * 4 + g];
        float ics[4];
#pragma unroll
        for (int c = 0; c < 4; c++)
            ics[c] = 1.0f / colsum[b * S_ + s0 + c * 16 + lr];
#pragma unroll
        for (int r = 0; r < 4; r++)
#pragma unroll
            for (int c = 0; c < 4; c++)
#pragma unroll
                for (int g = 0; g < 4; g++) {
                    const float p = acc[r][c][g];
                    acc[r][c][g] = p * p * (irs[r][g] * ics[c]);
                }

        // store conf: D layout col=lane&15 (s), row=quad*4+reg (l)
        float* pb = conf + (size_t)b * L_ * S_;
#pragma unroll
        for (int r = 0; r < 4; r++)
#pragma unroll
            for (int g = 0; g < 4; g++) {
                const int row = l0 + r * 16 + quad * 4 + g;
                float* prow = pb + (size_t)row * S_ + s0 + lr;
#pragma unroll
                for (int c = 0; c < 4; c++) prow[c * 16] = acc[r][c][g];
            }

        // row maxes + lane-local overall max (for sparse candidate gate)
        float lane_max = 0.f;
#pragma unroll
        for (int r = 0; r < 4; r++)
#pragma unroll
            for (int g = 0; g < 4; g++) {
                float m = fmaxf(fmaxf(acc[r][0][g], acc[r][1][g]),
                                fmaxf(acc[r][2][g], acc[r][3][g]));
                lane_max = fmaxf(lane_max, m);
                m = fmaxf(m, __shfl_xor(m, 1, 64));
                m = fmaxf(m, __shfl_xor(m, 2, 64));
                m = fmaxf(m, __shfl_xor(m, 4, 64));
                m = fmaxf(m, __shfl_xor(m, 8, 64));
                if (lr == 0) {
                    const int row = l0 + r * 16 + quad * 4 + g;
                    atomicMax((unsigned*)rowmax + b * L_ + row, __float_as_uint(m));
                }
            }
        // col maxes
#pragma unroll
        for (int c = 0; c < 4; c++) {
            float v = 0.f;
#pragma unroll
            for (int r = 0; r < 4; r++)
#pragma unroll
                for (int g = 0; g < 4; g++) v = fmaxf(v, acc[r][c][g]);
            v = fmaxf(v, __shfl_xor(v, 16, 64));
            v = fmaxf(v, __shfl_xor(v, 32, 64));
            if (quad == 0)
                atomicMax((unsigned*)colmax + b * S_ + s0 + c * 16 + lr, __float_as_uint(v));
        }

        // sparse candidate extraction (expected ~0 hits with these inputs)
        if (__any(lane_max > THR)) {
#pragma unroll
            for (int r = 0; r < 4; r++)
#pragma unroll
                for (int c = 0; c < 4; c++)
#pragma unroll
                    for (int g = 0; g < 4; g++) {
                        const float v = acc[r][c][g];
                        if (v > THR) {
                            const int l = l0 + r * 16 + quad * 4 + g;
                            const int s = s0 + c * 16 + lr;
                            const int lh = l / 80, lw = l % 80;
                            const int sh = s / 80, sw = s % 80;
                            if (lh >= 2 && lh < 58 && lw >= 2 && lw < 78 &&
                                sh >= 2 && sh < 58 && sw >= 2 && sw < 78) {
                                unsigned idx = atomicAdd(cand_cnt, 1u);
                                if (idx < CAND_CAP)
                                    cand_list[idx] = ((unsigned)b << 26) |
                                                     ((unsigned)l << 13) | (unsigned)s;
                            }
                        }
                    }
        }
    }
}

// per candidate: score = rowmax[l]*colmax[s]; best-per-row via packed u64 atomicMax.
// key = score_bits<<32 | (~s) -> max score, tie broken toward smallest s
// (matches jnp.argmax first-index semantics).
__global__ void k_score(const unsigned* __restrict__ cand_cnt,
                        const unsigned* __restrict__ cand_list,
                        const float* __restrict__ rowmax,
                        const float* __restrict__ colmax,
                        unsigned long long* __restrict__ best) {
    const unsigned n = min(*cand_cnt, CAND_CAP);
    for (unsigned i = blockIdx.x * blockDim.x + threadIdx.x; i < n;
         i += gridDim.x * blockDim.x) {
        const unsigned pk = cand_list[i];
        const int b = pk >> 26;
        const int l = (pk >> 13) & 8191;
        const int s = pk & 8191;
        const float sc = rowmax[b * L_ + l] * colmax[b * S_ + s];
        const unsigned long long key =
            ((unsigned long long)__float_as_uint(sc) << 32) |
            (unsigned long long)(0xFFFFFFFFu - (unsigned)s);
        atomicMax(best + b * L_ + l, key);
    }
}

__global__ void k_emit(const float* __restrict__ conf,
                       const unsigned long long* __restrict__ best,
                       float* __restrict__ o_match, float* __restrict__ o_sids,
                       float* __restrict__ o_mconf, float* __restrict__ o_kp0,
                       float* __restrict__ o_kp1) {
    const int i = blockIdx.x * blockDim.x + threadIdx.x;   // b*L + l
    if (i >= B_ * L_) return;
    const int b = i / L_;
    const int l = i - b * L_;
    const unsigned long long key = best[i];
    const bool match = key != 0ull;
    const int sid = match ? (int)(0xFFFFFFFFu - (unsigned)(key & 0xFFFFFFFFull)) : 0;
    const float mc = match ? conf[(size_t)i * S_ + sid] : 0.0f;
    o_match[i] = match ? 1.0f : 0.0f;
    o_sids[i]  = (float)sid;
    o_mconf[i] = mc;
    o_kp1[i * 2 + 0] = (float)(sid % 80) * KPT_SCALE;
    o_kp1[i * 2 + 1] = (float)(sid / 80) * KPT_SCALE;
    if (b == 0) {
        o_kp0[l * 2 + 0] = (float)(l % 80) * KPT_SCALE;
        o_kp0[l * 2 + 1] = (float)(l / 80) * KPT_SCALE;
    }
}

extern "C" void kernel_launch(void* const* d_in, const int* in_sizes, int n_in,
                              void* d_out, int out_size, void* d_ws, size_t ws_size,
                              hipStream_t stream) {
    const float* f0 = (const float*)d_in[0];
    const float* f1 = (const float*)d_in[1];
    float* out = (float*)d_out;

    float* conf_o  = out;                       // B*L*S = 92,160,000
    float* o_match = out + (size_t)92160000;    // B*L
    float* o_sids  = o_match + 19200;
    float* o_mconf = o_sids + 19200;
    float* o_kp0   = o_mconf + 19200;           // L*2
    float* o_kp1   = o_kp0 + 9600;              // B*L*2

    float* wsf    = (float*)d_ws;
    float* rowsum = wsf;
    float* colsum = wsf + 19200;
    float* rowmax = wsf + 38400;
    float* colmax = wsf + 57600;
    unsigned long long* best = (unsigned long long*)(wsf + 76800);
    unsigned* cand_cnt  = (unsigned*)(wsf + WS_CAND_CNT);
    unsigned* cand_list = (unsigned*)(wsf + WS_CAND_LIST);
    ushort* f0b = (ushort*)(wsf + WS_BF16);
    ushort* f1b = f0b + (size_t)B_ * L_ * C_;

    k_init<<<(WS_ZERO_N + 255) / 256, 256, 0, stream>>>(wsf);
    k_cast<<<4800, 256, 0, stream>>>(f0, f1, f0b, f1b);
    k_gemm<0><<<dim3(19, 75, B_), 256, 0, stream>>>(
        f0b, f1b, conf_o, rowsum, colsum, rowmax, colmax, cand_cnt, cand_list);
    k_gemm<1><<<dim3(19, 75, B_), 256, 0, stream>>>(
        f0b, f1b, conf_o, rowsum, colsum, rowmax, colmax, cand_cnt, cand_list);
    k_score<<<64, 256, 0, stream>>>(cand_cnt, cand_list, rowmax, colmax, best);
    k_emit<<<75, 256, 0, stream>>>(conf_o, best, o_match, o_sids, o_mconf, o_kp0, o_kp1);
}

// Round 2
// 645.984 us; speedup vs baseline: 1.2214x; 1.2214x over previous
//
#include <hip/hip_runtime.h>
#include <math.h>

#define B_ 4
#define L_ 4800
#define S_ 4800
#define C_ 256
#define LP_ 4864            // padded row count: 38 * 128
#define THR 0.2f
#define SIM_SCALE 0.0390625f   // 1/(256*0.1)
#define KPT_SCALE 8.0f
#define CAND_CAP 262144u

typedef short bf16x8 __attribute__((ext_vector_type(8)));   // 8 bf16 in 4 VGPRs
typedef float f32x4  __attribute__((ext_vector_type(4)));

// ---------------- ws layout (float slots) ----------------
// [0,19200)        rowsum   (B*L)
// [19200,38400)    colsum   (B*S)
// [38400,57600)    rowmax   (B*L)   (f32 bits via uint atomicMax, values >= 0)
// [57600,76800)    colmax   (B*S)
// [76800,115200)   bestkey  (B*L u64: score_bits<<32 | ~s)
// [115200]         cand_cnt (uint)
// [115208, +CAND_CAP) cand list (uint packed b<<26|l<<13|s)
// then f0b bf16 (B*LP*C), f1b bf16 (B*LP*C)  -- row-padded to 4864
#define WS_ZERO_N 115204
#define WS_CAND_CNT 115200
#define WS_CAND_LIST 115208
#define WS_BF16 (115208 + CAND_CAP)

__device__ __forceinline__ unsigned short f2bf(float x) {
    union { float f; unsigned int u; } v; v.f = x;
    unsigned int r = v.u + 0x7fffu + ((v.u >> 16) & 1u);   // RNE
    return (unsigned short)(r >> 16);
}

__device__ __forceinline__ void gload_lds16(const ushort* g, ushort* l) {
    __builtin_amdgcn_global_load_lds(
        (const __attribute__((address_space(1))) unsigned int*)g,
        (__attribute__((address_space(3))) unsigned int*)l,
        16, 0, 0);
}

// cast f32 -> bf16 into row-padded buffers; also zeroes the accumulator/ws head.
__global__ void k_cast(const float* __restrict__ f0, const float* __restrict__ f1,
                       ushort* __restrict__ f0b, ushort* __restrict__ f1b,
                       float* __restrict__ ws) {
    const int i = blockIdx.x * blockDim.x + threadIdx.x;   // float4 index
    if (i < WS_ZERO_N) ws[i] = 0.0f;
    if (i * 4 >= B_ * L_ * C_) return;
    const int perb = L_ * C_ / 4;          // 307200 float4 per batch
    const int b    = i / perb;
    const int rem  = i - b * perb;
    float4 a = ((const float4*)f0)[i];
    float4 v = ((const float4*)f1)[i];
    ushort4 oa, ob;
    oa.x = f2bf(a.x); oa.y = f2bf(a.y); oa.z = f2bf(a.z); oa.w = f2bf(a.w);
    ob.x = f2bf(v.x); ob.y = f2bf(v.y); ob.z = f2bf(v.z); ob.w = f2bf(v.w);
    const int o = b * (LP_ * C_ / 4) + rem;
    ((ushort4*)f0b)[o] = oa;
    ((ushort4*)f1b)[o] = ob;
}

// m97-structure GEMM: 128x128 tile per 256-thread block (4 waves, each a 64x64
// quadrant), BK=32 staged via global_load_lds(16B), 8x ds_read_b128 + 16 MFMA
// per K-step per wave. p = exp(sim * SIM_SCALE).
// PASS 0: rowsum/colsum of p (no conf store).
// PASS 1: conf = p^2/(rowsum*colsum); store conf; rowmax/colmax; sparse cands.
template <int PASS>
__global__ __launch_bounds__(256) void k_gemm(
        const ushort* __restrict__ f0b, const ushort* __restrict__ f1b,
        float* __restrict__ conf,
        float* __restrict__ rowsum, float* __restrict__ colsum,
        float* __restrict__ rowmax, float* __restrict__ colmax,
        unsigned* __restrict__ cand_cnt, unsigned* __restrict__ cand_list) {
    const int b    = blockIdx.z;
    const int l0   = blockIdx.y * 128;
    const int n0   = blockIdx.x * 128;
    const int t    = threadIdx.x;
    const int lane = t & 63;
    const int wid  = t >> 6;
    const int quad = lane >> 4;
    const int lr   = lane & 15;
    const int wr   = wid >> 1, wc = wid & 1;   // wave quadrant in the 128x128 tile
    const int lw0  = l0 + wr * 64;             // wave row base (l)
    const int nw0  = n0 + wc * 64;             // wave col base (s)

    __shared__ ushort lA[128 * 32];
    __shared__ ushort lB[128 * 32];

    const ushort* A  = f0b + (size_t)b * LP_ * C_;
    const ushort* Bm = f1b + (size_t)b * LP_ * C_;

    f32x4 acc[4][4];
#pragma unroll
    for (int r = 0; r < 4; r++)
#pragma unroll
        for (int c = 0; c < 4; c++) acc[r][c] = (f32x4){0.f, 0.f, 0.f, 0.f};

    for (int kk = 0; kk < C_; kk += 32) {
        // stage A[128][32], B[128][32]: 2 global_load_lds(16B) issues each
#pragma unroll
        for (int i = 0; i < 2; i++) {
            const int e   = i * 256 + t;        // 0..511
            const int row = e >> 2;             // 4 chunks of 8 bf16 per row
            const int ch  = e & 3;
            gload_lds16(A  + (size_t)(l0 + row) * C_ + kk + ch * 8, &lA[e * 8]);
            gload_lds16(Bm + (size_t)(n0 + row) * C_ + kk + ch * 8, &lB[e * 8]);
        }
        __syncthreads();                        // drains vmcnt before reads
        bf16x8 af[4], bf[4];
#pragma unroll
        for (int r = 0; r < 4; r++)
            af[r] = *(const bf16x8*)&lA[(wr * 64 + r * 16 + lr) * 32 + quad * 8];
#pragma unroll
        for (int c = 0; c < 4; c++)
            bf[c] = *(const bf16x8*)&lB[(wc * 64 + c * 16 + lr) * 32 + quad * 8];
#pragma unroll
        for (int r = 0; r < 4; r++)
#pragma unroll
            for (int c = 0; c < 4; c++)
                acc[r][c] = __builtin_amdgcn_mfma_f32_16x16x32_bf16(af[r], bf[c], acc[r][c], 0, 0, 0);
        __syncthreads();                        // LDS reuse next K-step
    }

    // p = exp(sim)
#pragma unroll
    for (int r = 0; r < 4; r++)
#pragma unroll
        for (int c = 0; c < 4; c++)
#pragma unroll
            for (int g = 0; g < 4; g++)
                acc[r][c][g] = __expf(acc[r][c][g] * SIM_SCALE);

    // zero padded rows/cols (edge blocks only); cndmask is NaN/inf-safe
    const bool edge = (lw0 + 63 >= L_) || (nw0 + 63 >= S_);
    if (edge) {
#pragma unroll
        for (int r = 0; r < 4; r++)
#pragma unroll
            for (int c = 0; c < 4; c++)
#pragma unroll
                for (int g = 0; g < 4; g++) {
                    const int l = lw0 + r * 16 + quad * 4 + g;
                    const int s = nw0 + c * 16 + lr;
                    if (l >= L_ || s >= S_) acc[r][c][g] = 0.f;
                }
    }

    if constexpr (PASS == 0) {
        // row sums over this wave's 64 s-cols
#pragma unroll
        for (int r = 0; r < 4; r++)
#pragma unroll
            for (int g = 0; g < 4; g++) {
                float v = acc[r][0][g] + acc[r][1][g] + acc[r][2][g] + acc[r][3][g];
                v += __shfl_xor(v, 1, 64);
                v += __shfl_xor(v, 2, 64);
                v += __shfl_xor(v, 4, 64);
                v += __shfl_xor(v, 8, 64);
                const int row = lw0 + r * 16 + quad * 4 + g;
                if (lr == 0 && row < L_) atomicAdd(rowsum + b * L_ + row, v);
            }
        // col sums over this wave's 64 l-rows
#pragma unroll
        for (int c = 0; c < 4; c++) {
            float v = 0.f;
#pragma unroll
            for (int r = 0; r < 4; r++)
#pragma unroll
                for (int g = 0; g < 4; g++) v += acc[r][c][g];
            v += __shfl_xor(v, 16, 64);
            v += __shfl_xor(v, 32, 64);
            const int s = nw0 + c * 16 + lr;
            if (quad == 0 && s < S_) atomicAdd(colsum + b * S_ + s, v);
        }
    } else {
        // conf = p^2 / (rowsum * colsum)
        float irs[4][4];
#pragma unroll
        for (int r = 0; r < 4; r++)
#pragma unroll
            for (int g = 0; g < 4; g++) {
                const int l = lw0 + r * 16 + quad * 4 + g;
                irs[r][g] = 1.0f / rowsum[b * L_ + (l < L_ ? l : L_ - 1)];
            }
        float ics[4];
#pragma unroll
        for (int c = 0; c < 4; c++) {
            const int s = nw0 + c * 16 + lr;
            ics[c] = 1.0f / colsum[b * S_ + (s < S_ ? s : S_ - 1)];
        }
#pragma unroll
        for (int r = 0; r < 4; r++)
#pragma unroll
            for (int c = 0; c < 4; c++)
#pragma unroll
                for (int g = 0; g < 4; g++) {
                    const float p = acc[r][c][g];
                    acc[r][c][g] = p * p * (irs[r][g] * ics[c]);
                }

        // store conf: D layout col=lane&15 (s), row=quad*4+reg (l)
        float* pb = conf + (size_t)b * L_ * S_;
        if (!edge) {
#pragma unroll
            for (int r = 0; r < 4; r++)
#pragma unroll
                for (int g = 0; g < 4; g++) {
                    const int row = lw0 + r * 16 + quad * 4 + g;
                    float* prow = pb + (size_t)row * S_ + nw0 + lr;
#pragma unroll
                    for (int c = 0; c < 4; c++) prow[c * 16] = acc[r][c][g];
                }
        } else {
#pragma unroll
            for (int r = 0; r < 4; r++)
#pragma unroll
                for (int g = 0; g < 4; g++) {
                    const int row = lw0 + r * 16 + quad * 4 + g;
                    if (row < L_) {
                        float* prow = pb + (size_t)row * S_ + nw0 + lr;
#pragma unroll
                        for (int c = 0; c < 4; c++)
                            if (nw0 + c * 16 + lr < S_) prow[c * 16] = acc[r][c][g];
                    }
                }
        }

        // row maxes + lane-local overall max (sparse candidate gate)
        float lane_max = 0.f;
#pragma unroll
        for (int r = 0; r < 4; r++)
#pragma unroll
            for (int g = 0; g < 4; g++) {
                float m = fmaxf(fmaxf(acc[r][0][g], acc[r][1][g]),
                                fmaxf(acc[r][2][g], acc[r][3][g]));
                lane_max = fmaxf(lane_max, m);
                m = fmaxf(m, __shfl_xor(m, 1, 64));
                m = fmaxf(m, __shfl_xor(m, 2, 64));
                m = fmaxf(m, __shfl_xor(m, 4, 64));
                m = fmaxf(m, __shfl_xor(m, 8, 64));
                const int row = lw0 + r * 16 + quad * 4 + g;
                if (lr == 0 && row < L_)
                    atomicMax((unsigned*)rowmax + b * L_ + row, __float_as_uint(m));
            }
        // col maxes
#pragma unroll
        for (int c = 0; c < 4; c++) {
            float v = 0.f;
#pragma unroll
            for (int r = 0; r < 4; r++)
#pragma unroll
                for (int g = 0; g < 4; g++) v = fmaxf(v, acc[r][c][g]);
            v = fmaxf(v, __shfl_xor(v, 16, 64));
            v = fmaxf(v, __shfl_xor(v, 32, 64));
            const int s = nw0 + c * 16 + lr;
            if (quad == 0 && s < S_)
                atomicMax((unsigned*)colmax + b * S_ + s, __float_as_uint(v));
        }

        // sparse candidate extraction (expected ~0 hits with these inputs);
        // border check (lh<58 -> l<4640) subsumes the padding-validity check.
        if (__any(lane_max > THR)) {
#pragma unroll
            for (int r = 0; r < 4; r++)
#pragma unroll
                for (int c = 0; c < 4; c++)
#pragma unroll
                    for (int g = 0; g < 4; g++) {
                        const float v = acc[r][c][g];
                        if (v > THR) {
                            const int l = lw0 + r * 16 + quad * 4 + g;
                            const int s = nw0 + c * 16 + lr;
                            const int lh = l / 80, lw = l % 80;
                            const int sh = s / 80, sw = s % 80;
                            if (lh >= 2 && lh < 58 && lw >= 2 && lw < 78 &&
                                sh >= 2 && sh < 58 && sw >= 2 && sw < 78) {
                                unsigned idx = atomicAdd(cand_cnt, 1u);
                                if (idx < CAND_CAP)
                                    cand_list[idx] = ((unsigned)b << 26) |
                                                     ((unsigned)l << 13) | (unsigned)s;
                            }
                        }
                    }
        }
    }
}

// per candidate: score = rowmax[l]*colmax[s]; best-per-row via packed u64 atomicMax.
// key = score_bits<<32 | ~s -> max score, ties toward smallest s (jnp.argmax).
__global__ void k_score(const unsigned* __restrict__ cand_cnt,
                        const unsigned* __restrict__ cand_list,
                        const float* __restrict__ rowmax,
                        const float* __restrict__ colmax,
                        unsigned long long* __restrict__ best) {
    const unsigned n = min(*cand_cnt, CAND_CAP);
    for (unsigned i = blockIdx.x * blockDim.x + threadIdx.x; i < n;
         i += gridDim.x * blockDim.x) {
        const unsigned pk = cand_list[i];
        const int b = pk >> 26;
        const int l = (pk >> 13) & 8191;
        const int s = pk & 8191;
        const float sc = rowmax[b * L_ + l] * colmax[b * S_ + s];
        const unsigned long long key =
            ((unsigned long long)__float_as_uint(sc) << 32) |
            (unsigned long long)(0xFFFFFFFFu - (unsigned)s);
        atomicMax(best + b * L_ + l, key);
    }
}

__global__ void k_emit(const float* __restrict__ conf,
                       const unsigned long long* __restrict__ best,
                       float* __restrict__ o_match, float* __restrict__ o_sids,
                       float* __restrict__ o_mconf, float* __restrict__ o_kp0,
                       float* __restrict__ o_kp1) {
    const int i = blockIdx.x * blockDim.x + threadIdx.x;   // b*L + l
    if (i >= B_ * L_) return;
    const int b = i / L_;
    const int l = i - b * L_;
    const unsigned long long key = best[i];
    const bool match = key != 0ull;
    const int sid = match ? (int)(0xFFFFFFFFu - (unsigned)(key & 0xFFFFFFFFull)) : 0;
    const float mc = match ? conf[(size_t)i * S_ + sid] : 0.0f;
    o_match[i] = match ? 1.0f : 0.0f;
    o_sids[i]  = (float)sid;
    o_mconf[i] = mc;
    o_kp1[i * 2 + 0] = (float)(sid % 80) * KPT_SCALE;
    o_kp1[i * 2 + 1] = (float)(sid / 80) * KPT_SCALE;
    if (b == 0) {
        o_kp0[l * 2 + 0] = (float)(l % 80) * KPT_SCALE;
        o_kp0[l * 2 + 1] = (float)(l / 80) * KPT_SCALE;
    }
}

extern "C" void kernel_launch(void* const* d_in, const int* in_sizes, int n_in,
                              void* d_out, int out_size, void* d_ws, size_t ws_size,
                              hipStream_t stream) {
    const float* f0 = (const float*)d_in[0];
    const float* f1 = (const float*)d_in[1];
    float* out = (float*)d_out;

    float* conf_o  = out;                       // B*L*S = 92,160,000
    float* o_match = out + (size_t)92160000;    // B*L
    float* o_sids  = o_match + 19200;
    float* o_mconf = o_sids + 19200;
    float* o_kp0   = o_mconf + 19200;           // L*2
    float* o_kp1   = o_kp0 + 9600;              // B*L*2

    float* wsf    = (float*)d_ws;
    float* rowsum = wsf;
    float* colsum = wsf + 19200;
    float* rowmax = wsf + 38400;
    float* colmax = wsf + 57600;
    unsigned long long* best = (unsigned long long*)(wsf + 76800);
    unsigned* cand_cnt  = (unsigned*)(wsf + WS_CAND_CNT);
    unsigned* cand_list = (unsigned*)(wsf + WS_CAND_LIST);
    ushort* f0b = (ushort*)(wsf + WS_BF16);
    ushort* f1b = f0b + (size_t)B_ * LP_ * C_;

    k_cast<<<4800, 256, 0, stream>>>(f0, f1, f0b, f1b, wsf);
    k_gemm<0><<<dim3(38, 38, B_), 256, 0, stream>>>(
        f0b, f1b, conf_o, rowsum, colsum, rowmax, colmax, cand_cnt, cand_list);
    k_gemm<1><<<dim3(38, 38, B_), 256, 0, stream>>>(
        f0b, f1b, conf_o, rowsum, colsum, rowmax, colmax, cand_cnt, cand_list);
    k_score<<<64, 256, 0, stream>>>(cand_cnt, cand_list, rowmax, colmax, best);
    k_emit<<<75, 256, 0, stream>>>(conf_o, best, o_match, o_sids, o_mconf, o_kp0, o_kp1);
}

// Round 3
// 624.722 us; speedup vs baseline: 1.2630x; 1.0340x over previous
//
#include <hip/hip_runtime.h>
#include <math.h>

#define B_ 4
#define L_ 4800
#define S_ 4800
#define C_ 256
#define LP_ 4864            // padded row count: 38 * 128
#define THR 0.2f
#define SIM_SCALE 0.0390625f   // 1/(256*0.1)
#define KPT_SCALE 8.0f
#define CAND_CAP 262144u

typedef short bf16x8 __attribute__((ext_vector_type(8)));   // 8 bf16 in 4 VGPRs
typedef float f32x4  __attribute__((ext_vector_type(4)));

// ---------------- ws layout (float slots) ----------------
// [0,19200)        rowsum   (B*L)
// [19200,38400)    colsum   (B*S)
// [38400,57600)    rowmax   (B*L)   (f32 bits via uint atomicMax, values >= 0)
// [57600,76800)    colmax   (B*S)
// [76800,115200)   bestkey  (B*L u64: score_bits<<32 | ~s)
// [115200]         cand_cnt (uint)
// [115208, +CAND_CAP) cand list (uint packed b<<26|l<<13|s)
// then f0b bf16 (B*LP*C), f1b bf16 (B*LP*C)  -- row-padded to 4864
#define WS_ZERO_N 115204
#define WS_CAND_CNT 115200
#define WS_CAND_LIST 115208
#define WS_BF16 (115208 + CAND_CAP)

__device__ __forceinline__ unsigned short f2bf(float x) {
    union { float f; unsigned int u; } v; v.f = x;
    unsigned int r = v.u + 0x7fffu + ((v.u >> 16) & 1u);   // RNE
    return (unsigned short)(r >> 16);
}

__device__ __forceinline__ void gload_lds16(const ushort* g, ushort* l) {
    __builtin_amdgcn_global_load_lds(
        (const __attribute__((address_space(1))) unsigned int*)g,
        (__attribute__((address_space(3))) unsigned int*)l,
        16, 0, 0);
}

// cast f32 -> bf16 into row-padded buffers; also zeroes the accumulator/ws head.
__global__ void k_cast(const float* __restrict__ f0, const float* __restrict__ f1,
                       ushort* __restrict__ f0b, ushort* __restrict__ f1b,
                       float* __restrict__ ws) {
    const int i = blockIdx.x * blockDim.x + threadIdx.x;   // float4 index
    if (i < WS_ZERO_N) ws[i] = 0.0f;
    if (i * 4 >= B_ * L_ * C_) return;
    const int perb = L_ * C_ / 4;          // 307200 float4 per batch
    const int b    = i / perb;
    const int rem  = i - b * perb;
    float4 a = ((const float4*)f0)[i];
    float4 v = ((const float4*)f1)[i];
    ushort4 oa, ob;
    oa.x = f2bf(a.x); oa.y = f2bf(a.y); oa.z = f2bf(a.z); oa.w = f2bf(a.w);
    ob.x = f2bf(v.x); ob.y = f2bf(v.y); ob.z = f2bf(v.z); ob.w = f2bf(v.w);
    const int o = b * (LP_ * C_ / 4) + rem;
    ((ushort4*)f0b)[o] = oa;
    ((ushort4*)f1b)[o] = ob;
}

// m97-structure GEMM, SINGLE pass: 128x128 tile per 256-thread block (4 waves,
// each a 64x64 quadrant), BK=32 staged via global_load_lds(16B).
// Computes p = exp(sim*SIM_SCALE), stores p into the conf buffer (normalized
// later by k_norm), and accumulates rowsum/colsum atomics.
__global__ __launch_bounds__(256) void k_gemm(
        const ushort* __restrict__ f0b, const ushort* __restrict__ f1b,
        float* __restrict__ conf,
        float* __restrict__ rowsum, float* __restrict__ colsum) {
    const int b    = blockIdx.z;
    const int l0   = blockIdx.y * 128;
    const int n0   = blockIdx.x * 128;
    const int t    = threadIdx.x;
    const int lane = t & 63;
    const int wid  = t >> 6;
    const int quad = lane >> 4;
    const int lr   = lane & 15;
    const int wr   = wid >> 1, wc = wid & 1;   // wave quadrant in the 128x128 tile
    const int lw0  = l0 + wr * 64;             // wave row base (l)
    const int nw0  = n0 + wc * 64;             // wave col base (s)

    __shared__ ushort lA[128 * 32];
    __shared__ ushort lB[128 * 32];

    const ushort* A  = f0b + (size_t)b * LP_ * C_;
    const ushort* Bm = f1b + (size_t)b * LP_ * C_;

    f32x4 acc[4][4];
#pragma unroll
    for (int r = 0; r < 4; r++)
#pragma unroll
        for (int c = 0; c < 4; c++) acc[r][c] = (f32x4){0.f, 0.f, 0.f, 0.f};

    for (int kk = 0; kk < C_; kk += 32) {
        // stage A[128][32], B[128][32]: 2 global_load_lds(16B) issues each
#pragma unroll
        for (int i = 0; i < 2; i++) {
            const int e   = i * 256 + t;        // 0..511
            const int row = e >> 2;             // 4 chunks of 8 bf16 per row
            const int ch  = e & 3;
            gload_lds16(A  + (size_t)(l0 + row) * C_ + kk + ch * 8, &lA[e * 8]);
            gload_lds16(Bm + (size_t)(n0 + row) * C_ + kk + ch * 8, &lB[e * 8]);
        }
        __syncthreads();                        // drains vmcnt before reads
        bf16x8 af[4], bf[4];
#pragma unroll
        for (int r = 0; r < 4; r++)
            af[r] = *(const bf16x8*)&lA[(wr * 64 + r * 16 + lr) * 32 + quad * 8];
#pragma unroll
        for (int c = 0; c < 4; c++)
            bf[c] = *(const bf16x8*)&lB[(wc * 64 + c * 16 + lr) * 32 + quad * 8];
#pragma unroll
        for (int r = 0; r < 4; r++)
#pragma unroll
            for (int c = 0; c < 4; c++)
                acc[r][c] = __builtin_amdgcn_mfma_f32_16x16x32_bf16(af[r], bf[c], acc[r][c], 0, 0, 0);
        __syncthreads();                        // LDS reuse next K-step
    }

    // p = exp(sim)
#pragma unroll
    for (int r = 0; r < 4; r++)
#pragma unroll
        for (int c = 0; c < 4; c++)
#pragma unroll
            for (int g = 0; g < 4; g++)
                acc[r][c][g] = __expf(acc[r][c][g] * SIM_SCALE);

    // zero padded rows/cols (edge blocks only) so sums stay clean
    const bool edge = (lw0 + 63 >= L_) || (nw0 + 63 >= S_);
    if (edge) {
#pragma unroll
        for (int r = 0; r < 4; r++)
#pragma unroll
            for (int c = 0; c < 4; c++)
#pragma unroll
                for (int g = 0; g < 4; g++) {
                    const int l = lw0 + r * 16 + quad * 4 + g;
                    const int s = nw0 + c * 16 + lr;
                    if (l >= L_ || s >= S_) acc[r][c][g] = 0.f;
                }
    }

    // store p: D layout col=lane&15 (s), row=quad*4+reg (l)
    float* pb = conf + (size_t)b * L_ * S_;
    if (!edge) {
#pragma unroll
        for (int r = 0; r < 4; r++)
#pragma unroll
            for (int g = 0; g < 4; g++) {
                const int row = lw0 + r * 16 + quad * 4 + g;
                float* prow = pb + (size_t)row * S_ + nw0 + lr;
#pragma unroll
                for (int c = 0; c < 4; c++) prow[c * 16] = acc[r][c][g];
            }
    } else {
#pragma unroll
        for (int r = 0; r < 4; r++)
#pragma unroll
            for (int g = 0; g < 4; g++) {
                const int row = lw0 + r * 16 + quad * 4 + g;
                if (row < L_) {
                    float* prow = pb + (size_t)row * S_ + nw0 + lr;
#pragma unroll
                    for (int c = 0; c < 4; c++)
                        if (nw0 + c * 16 + lr < S_) prow[c * 16] = acc[r][c][g];
                }
            }
    }

    // row sums over this wave's 64 s-cols
#pragma unroll
    for (int r = 0; r < 4; r++)
#pragma unroll
        for (int g = 0; g < 4; g++) {
            float v = acc[r][0][g] + acc[r][1][g] + acc[r][2][g] + acc[r][3][g];
            v += __shfl_xor(v, 1, 64);
            v += __shfl_xor(v, 2, 64);
            v += __shfl_xor(v, 4, 64);
            v += __shfl_xor(v, 8, 64);
            const int row = lw0 + r * 16 + quad * 4 + g;
            if (lr == 0 && row < L_) atomicAdd(rowsum + b * L_ + row, v);
        }
    // col sums over this wave's 64 l-rows
#pragma unroll
    for (int c = 0; c < 4; c++) {
        float v = 0.f;
#pragma unroll
        for (int r = 0; r < 4; r++)
#pragma unroll
            for (int g = 0; g < 4; g++) v += acc[r][c][g];
        v += __shfl_xor(v, 16, 64);
        v += __shfl_xor(v, 32, 64);
        const int s = nw0 + c * 16 + lr;
        if (quad == 0 && s < S_) atomicAdd(colsum + b * S_ + s, v);
    }
}

// In-place normalize: conf = p^2/(rowsum*colsum) over a 64x64 tile; per-tile
// row/col max via LDS + one global atomicMax each; sparse candidate extraction.
__global__ __launch_bounds__(256) void k_norm(
        float* __restrict__ conf,
        const float* __restrict__ rowsum, const float* __restrict__ colsum,
        float* __restrict__ rowmax, float* __restrict__ colmax,
        unsigned* __restrict__ cand_cnt, unsigned* __restrict__ cand_list) {
    const int b  = blockIdx.z;
    const int l0 = blockIdx.y * 64;
    const int s0 = blockIdx.x * 64;
    __shared__ unsigned rm[64], cm[64];
    const int t = threadIdx.x;
    if (t < 64) { rm[t] = 0u; cm[t] = 0u; }
    __syncthreads();
    const int c4 = t & 15, r0 = t >> 4;
    const int sbase = s0 + c4 * 4;
    const float4 cs = *(const float4*)(colsum + b * S_ + sbase);
    const float icx = 1.0f / cs.x, icy = 1.0f / cs.y, icz = 1.0f / cs.z, icw = 1.0f / cs.w;
    // s border validity for the 4 cols (s row = sbase/80 constant across j? no)
    float cmx = 0.f, cmy = 0.f, cmz = 0.f, cmw = 0.f;
    float* base = conf + (size_t)b * L_ * S_;
#pragma unroll
    for (int it = 0; it < 4; it++) {
        const int r = r0 + 16 * it;
        const int l = l0 + r;
        const float irs = 1.0f / rowsum[b * L_ + l];
        float* addr = base + (size_t)l * S_ + sbase;
        float4 p = *(float4*)addr;
        float4 cf;
        cf.x = p.x * p.x * (irs * icx);
        cf.y = p.y * p.y * (irs * icy);
        cf.z = p.z * p.z * (irs * icz);
        cf.w = p.w * p.w * (irs * icw);
        *(float4*)addr = cf;
        const float m = fmaxf(fmaxf(cf.x, cf.y), fmaxf(cf.z, cf.w));
        atomicMax(&rm[r], __float_as_uint(m));
        cmx = fmaxf(cmx, cf.x); cmy = fmaxf(cmy, cf.y);
        cmz = fmaxf(cmz, cf.z); cmw = fmaxf(cmw, cf.w);
        // sparse candidates (expected ~0 hits): conf>THR & border-valid
        if (m > THR) {
            const int lh = l / 80, lw = l % 80;
            if (lh >= 2 && lh < 58 && lw >= 2 && lw < 78) {
                const float cfa[4] = {cf.x, cf.y, cf.z, cf.w};
#pragma unroll
                for (int j = 0; j < 4; j++) {
                    if (cfa[j] > THR) {
                        const int s = sbase + j;
                        const int sh = s / 80, sw = s % 80;
                        if (sh >= 2 && sh < 58 && sw >= 2 && sw < 78) {
                            unsigned idx = atomicAdd(cand_cnt, 1u);
                            if (idx < CAND_CAP)
                                cand_list[idx] = ((unsigned)b << 26) |
                                                 ((unsigned)l << 13) | (unsigned)s;
                        }
                    }
                }
            }
        }
    }
    atomicMax(&cm[c4 * 4 + 0], __float_as_uint(cmx));
    atomicMax(&cm[c4 * 4 + 1], __float_as_uint(cmy));
    atomicMax(&cm[c4 * 4 + 2], __float_as_uint(cmz));
    atomicMax(&cm[c4 * 4 + 3], __float_as_uint(cmw));
    __syncthreads();
    if (t < 64) {
        atomicMax((unsigned*)rowmax + b * L_ + l0 + t, rm[t]);
        atomicMax((unsigned*)colmax + b * S_ + s0 + t, cm[t]);
    }
}

// per candidate: score = rowmax[l]*colmax[s]; best-per-row via packed u64 atomicMax.
// key = score_bits<<32 | ~s -> max score, ties toward smallest s (jnp.argmax).
__global__ void k_score(const unsigned* __restrict__ cand_cnt,
                        const unsigned* __restrict__ cand_list,
                        const float* __restrict__ rowmax,
                        const float* __restrict__ colmax,
                        unsigned long long* __restrict__ best) {
    const unsigned n = min(*cand_cnt, CAND_CAP);
    for (unsigned i = blockIdx.x * blockDim.x + threadIdx.x; i < n;
         i += gridDim.x * blockDim.x) {
        const unsigned pk = cand_list[i];
        const int b = pk >> 26;
        const int l = (pk >> 13) & 8191;
        const int s = pk & 8191;
        const float sc = rowmax[b * L_ + l] * colmax[b * S_ + s];
        const unsigned long long key =
            ((unsigned long long)__float_as_uint(sc) << 32) |
            (unsigned long long)(0xFFFFFFFFu - (unsigned)s);
        atomicMax(best + b * L_ + l, key);
    }
}

__global__ void k_emit(const float* __restrict__ conf,
                       const unsigned long long* __restrict__ best,
                       float* __restrict__ o_match, float* __restrict__ o_sids,
                       float* __restrict__ o_mconf, float* __restrict__ o_kp0,
                       float* __restrict__ o_kp1) {
    const int i = blockIdx.x * blockDim.x + threadIdx.x;   // b*L + l
    if (i >= B_ * L_) return;
    const int b = i / L_;
    const int l = i - b * L_;
    const unsigned long long key = best[i];
    const bool match = key != 0ull;
    const int sid = match ? (int)(0xFFFFFFFFu - (unsigned)(key & 0xFFFFFFFFull)) : 0;
    const float mc = match ? conf[(size_t)i * S_ + sid] : 0.0f;
    o_match[i] = match ? 1.0f : 0.0f;
    o_sids[i]  = (float)sid;
    o_mconf[i] = mc;
    o_kp1[i * 2 + 0] = (float)(sid % 80) * KPT_SCALE;
    o_kp1[i * 2 + 1] = (float)(sid / 80) * KPT_SCALE;
    if (b == 0) {
        o_kp0[l * 2 + 0] = (float)(l % 80) * KPT_SCALE;
        o_kp0[l * 2 + 1] = (float)(l / 80) * KPT_SCALE;
    }
}

extern "C" void kernel_launch(void* const* d_in, const int* in_sizes, int n_in,
                              void* d_out, int out_size, void* d_ws, size_t ws_size,
                              hipStream_t stream) {
    const float* f0 = (const float*)d_in[0];
    const float* f1 = (const float*)d_in[1];
    float* out = (float*)d_out;

    float* conf_o  = out;                       // B*L*S = 92,160,000
    float* o_match = out + (size_t)92160000;    // B*L
    float* o_sids  = o_match + 19200;
    float* o_mconf = o_sids + 19200;
    float* o_kp0   = o_mconf + 19200;           // L*2
    float* o_kp1   = o_kp0 + 9600;              // B*L*2

    float* wsf    = (float*)d_ws;
    float* rowsum = wsf;
    float* colsum = wsf + 19200;
    float* rowmax = wsf + 38400;
    float* colmax = wsf + 57600;
    unsigned long long* best = (unsigned long long*)(wsf + 76800);
    unsigned* cand_cnt  = (unsigned*)(wsf + WS_CAND_CNT);
    unsigned* cand_list = (unsigned*)(wsf + WS_CAND_LIST);
    ushort* f0b = (ushort*)(wsf + WS_BF16);
    ushort* f1b = f0b + (size_t)B_ * LP_ * C_;

    k_cast<<<4800, 256, 0, stream>>>(f0, f1, f0b, f1b, wsf);
    k_gemm<<<dim3(38, 38, B_), 256, 0, stream>>>(f0b, f1b, conf_o, rowsum, colsum);
    k_norm<<<dim3(75, 75, B_), 256, 0, stream>>>(conf_o, rowsum, colsum,
                                                 rowmax, colmax, cand_cnt, cand_list);
    k_score<<<64, 256, 0, stream>>>(cand_cnt, cand_list, rowmax, colmax, best);
    k_emit<<<75, 256, 0, stream>>>(conf_o, best, o_match, o_sids, o_mconf, o_kp0, o_kp1);
}